// Round 12
// baseline (1862.409 us; speedup 1.0000x reference)
//
#include <hip/hip_runtime.h>
#include <hip/hip_fp16.h>
#include <cstdint>

// mLstm  B=16, P=128, Q=256, D=128, H=128. fp32 in/out.
// R17 = R15 (best: 1270us seq) with the R16 accounting error fixed:
//  - D: whs in LDS as fp16 DWp (64KB, R16-proven numerics) instead of fp32
//    whs_l (135KB). The 71KB saved funds 4 LDS-resident F chunks (64KB):
//    stream 544 -> 480KB/step and D leaves the L2 path entirely.
//  - Phase C DELETED (-1 barrier, -wave0-only serialization): softmax stats
//    fused into D. Per-lane max over its 32 scores + shfl_xor(1,2,4) (lane
//    low bits = qgD) -> global max; pass2 accumulates sum(e*w), sum(e)
//    together; alpha = accw * rcp(acce). 32 redundant exps/thread, but on
//    all 1024 threads instead of 64.
//  - Cell phase reverts to R15 verbatim (coalesced writes; R16's fused cell
//    caused 4B-scatter write amplification, WRITE 3.1->5.0MB).
// 6 barriers/step. Keep: load-linear packs (R12), dot2+xh_h2 (R15),
// all-local 16 blocks (R5/R7-R10), no explicit prefetch regs (R13 lesson),
// no reg-resident weights (R6/R7 lesson).

__device__ __forceinline__ float bf2f(uint16_t u) {
  uint32_t x = ((uint32_t)u) << 16; float f; __builtin_memcpy(&f, &x, 4); return f;
}
__device__ __forceinline__ float load_in(const void* p, size_t i, int f32) {
  return f32 ? ((const float*)p)[i] : bf2f(((const uint16_t*)p)[i]);
}
__device__ __forceinline__ float frcp(float x) { return __builtin_amdgcn_rcpf(x); }
__device__ __forceinline__ float tanh_fast(float x) {
  float E = __expf(2.0f * x);
  return 1.0f - 2.0f * frcp(E + 1.0f);
}
__device__ __forceinline__ float sigm(float x) { return frcp(1.0f + __expf(-x)); }
__device__ __forceinline__ float2 h2f(uint32_t u) {
  __half2 h; __builtin_memcpy(&h, &u, 4); return __half22float2(h);
}
__device__ __forceinline__ uint32_t f2h(float a, float b) {
  __half2 h = __floats2half2_rn(a, b);
  uint32_t u; __builtin_memcpy(&u, &h, 4); return u;
}

typedef _Float16 h2v __attribute__((ext_vector_type(2)));
__device__ __forceinline__ float dot2(uint32_t w, uint32_t x, float acc) {
#if defined(__has_builtin)
#if __has_builtin(__builtin_amdgcn_fdot2)
  h2v a, b; __builtin_memcpy(&a, &w, 4); __builtin_memcpy(&b, &x, 4);
  return __builtin_amdgcn_fdot2(a, b, acc, false);
#else
  float2 af = h2f(w), bf = h2f(x);
  return fmaf(af.x, bf.x, fmaf(af.y, bf.y, acc));
#endif
#else
  float2 af = h2f(w), bf = h2f(x);
  return fmaf(af.x, bf.x, fmaf(af.y, bf.y, acc));
#endif
}

// ------------------------------------------------------------- detect kernel
__global__ void detect_kernel(const uint16_t* __restrict__ q16,
                              uint32_t* __restrict__ flag) {
  __shared__ int cnt;
  if (threadIdx.x == 0) cnt = 0;
  __syncthreads();
  int bad = 0;
  for (int i = threadIdx.x; i < 4096; i += 256) {
    int e = (q16[i] >> 7) & 0xFF;
    if (e > 0x8A) bad++;
  }
  atomicAdd(&cnt, bad);
  __syncthreads();
  if (threadIdx.x == 0) *flag = (cnt > 16) ? 1u : 0u;
}

// ------------------------------------------------- convert + pack (R12/R15 verbatim)
// Total 262144+8192+128+128+1+16384+98304+512 = 385793 -> grid 1508 x 256.
__global__ void pack2(const void* __restrict__ p,
                      const void* __restrict__ Wr,  const void* __restrict__ Wrb_,
                      const void* __restrict__ Wew_, const void* __restrict__ Web_,
                      const void* __restrict__ Wg,
                      const void* __restrict__ Wih, const void* __restrict__ Whh,
                      const void* __restrict__ bih, const void* __restrict__ bhh,
                      float* __restrict__ pf,
                      uint32_t* __restrict__ WrP, float* __restrict__ wrb,
                      float* __restrict__ wew, float* __restrict__ web,
                      uint32_t* __restrict__ WgP, uint32_t* __restrict__ WTP,
                      float* __restrict__ bbv,
                      const uint32_t* __restrict__ flag) {
  const int f32 = (int)*flag;
  long idx = (long)blockIdx.x * blockDim.x + threadIdx.x;
  if (idx < 262144) { pf[idx] = load_in(p, idx, f32); return; }
  idx -= 262144;
  if (idx < 8192) {
    int c = (int)(idx >> 2), w = (int)(idx & 3);
    int i = c >> 10, t = c & 1023;
    int jA = t >> 3, kgA = t & 7;
    int k = kgA * 16 + i * 8 + w * 2;
    WrP[idx] = f2h(load_in(Wr, (size_t)jA * 128 + k, f32),
                   load_in(Wr, (size_t)jA * 128 + k + 1, f32));
    return; }
  idx -= 8192;
  if (idx < 128) { wrb[idx] = load_in(Wrb_, idx, f32); return; }
  idx -= 128;
  if (idx < 128) { wew[idx] = load_in(Wew_, idx, f32); return; }
  idx -= 128;
  if (idx < 1) { web[0] = load_in(Web_, 0, f32); return; }
  idx -= 1;
  if (idx < 16384) {
    int c = (int)(idx >> 2), w = (int)(idx & 3);
    int i = c >> 10, t = c & 1023;
    int iE = t >> 2, kgE = t & 3;
    int k = kgE * 32 + i * 8 + w * 2;
    WgP[idx] = f2h(load_in(Wg, (size_t)iE * 256 + k, f32),
                   load_in(Wg, (size_t)iE * 256 + k + 1, f32));
    return; }
  idx -= 16384;
  if (idx < 98304) {
    int c = (int)(idx >> 2), w = (int)(idx & 3);
    int i = c >> 10, t = c & 1023;
    int iF = t >> 1, kgF = t & 1;
    int k = kgF * 192 + i * 8 + w * 2;
    float v0 = (k < 256) ? load_in(Wih, (size_t)iF * 256 + k, f32)
                         : load_in(Whh, (size_t)iF * 128 + (k - 256), f32);
    float v1 = (k + 1 < 256) ? load_in(Wih, (size_t)iF * 256 + k + 1, f32)
                             : load_in(Whh, (size_t)iF * 128 + (k + 1 - 256), f32);
    WTP[idx] = f2h(v0, v1);
    return; }
  idx -= 98304;
  if (idx < 512) { bbv[idx] = load_in(bih, idx, f32) + load_in(bhh, idx, f32); }
}

// --------------------------------------------- fused 3-way small GEMM (K=128)
__global__ __launch_bounds__(256) void gemm3(
    const void* __restrict__ q, const void* __restrict__ p,
    const void* __restrict__ Wsw, const void* __restrict__ Wsb,
    const void* __restrict__ Wtw, const void* __restrict__ Wtb,
    const void* __restrict__ Wgw, const void* __restrict__ Wgb,
    float* __restrict__ whs, float* __restrict__ wht, float* __restrict__ Gp,
    const uint32_t* __restrict__ flag) {
  __shared__ float A_l[16][128];
  __shared__ float W_l[64][129];
  const int f32 = (int)*flag;
  const int t = threadIdx.x;
  const void* A; const void* W; const void* bias; float* out;
  int lda = 128, ldw, w_off, C, r0;
  int blk = blockIdx.x;
  if (blk < 256)      { A = q; W = Wsw; bias = Wsb; out = whs; ldw = 128; w_off = 0;   C = 128; r0 = blk * 16; }
  else if (blk < 384) { A = p; W = Wtw; bias = Wtb; out = wht; ldw = 128; w_off = 0;   C = 128; r0 = (blk - 256) * 16; }
  else                { A = p; W = Wgw; bias = Wgb; out = Gp;  ldw = 256; w_off = 128; C = 256; r0 = (blk - 384) * 16; }
  for (int idx = t; idx < 16 * 128; idx += 256) {
    int rr = idx >> 7, kk = idx & 127;
    A_l[rr][kk] = load_in(A, (size_t)(r0 + rr) * lda + kk, f32);
  }
  const int c_l = t & 63, rg = t >> 6;
  for (int c0 = 0; c0 < C; c0 += 64) {
    __syncthreads();
    for (int idx = t; idx < 64 * 128; idx += 256) {
      int cc = idx >> 7, kk = idx & 127;
      W_l[cc][kk] = load_in(W, (size_t)w_off + (size_t)(c0 + cc) * ldw + kk, f32);
    }
    __syncthreads();
    float acc[4] = {0.f, 0.f, 0.f, 0.f};
    for (int k = 0; k < 128; k++) {
      float w = W_l[c_l][k];
#pragma unroll
      for (int x = 0; x < 4; x++) acc[x] = fmaf(A_l[rg * 4 + x][k], w, acc[x]);
    }
    float bv = load_in(bias, c0 + c_l, f32);
#pragma unroll
    for (int x = 0; x < 4; x++)
      out[(size_t)(r0 + rg * 4 + x) * C + c0 + c_l] = acc[x] + bv;
  }
}

// ---------------- actpack (R16 verbatim): TAp (tanh(whs) fp16, B-layout) +
// DWp (whs fp16, D-layout), both per-thread load-linear.
// DWp u32 o (in-batch 16384): i=o>>12; r=o&4095; t=r>>2; w=r&3; qgD=t&7;
//   hD=t>>3; q0=qgD+64i+16w -> pair (whs[b][q0][hD], whs[b][q0+8][hD])
// 2*262144 u32 -> 2048 blocks x 256.
__global__ void actpack(const float* __restrict__ whs,
                        uint32_t* __restrict__ TAp, uint32_t* __restrict__ DWp) {
  int o = blockIdx.x * 256 + threadIdx.x;
  if (o < 262144) {
    int b = o >> 14, r = o & 16383;
    int c = r >> 2, w = r & 3;
    int i = c >> 10, t = c & 1023;
    int qB = t >> 2, hgB = t & 3;
    int h = hgB * 32 + i * 8 + w * 2;
    const float* base = whs + ((size_t)b * 256 + qB) * 128 + h;
    TAp[o] = f2h(tanhf(base[0]), tanhf(base[1]));
  } else {
    o -= 262144;
    int b = o >> 14, r2 = o & 16383;
    int i = r2 >> 12, r = r2 & 4095;
    int t = r >> 2, w = r & 3;
    int qgD = t & 7, hD = t >> 3;
    int q0 = qgD + 64 * i + 16 * w;
    const float* base = whs + (size_t)b * 32768;
    DWp[o] = f2h(base[(size_t)q0 * 128 + hD], base[(size_t)(q0 + 8) * 128 + hD]);
  }
}

// ---------------------------------------------------------- sequential kernel
#define TUIDX(j) ((((j) >> 5) * 36) + ((j) & 31))
#define SCIDX(q) ((((q) >> 5) * 36) + ((q) & 31))
#define AIDX(h)  ((((h) >> 5) * 36) + ((h) & 31))
#define HIDX(k)  ((((k) >> 4) * 20) + ((k) & 15))

__global__ __launch_bounds__(1024) void mlstm_seq13(
    const float* __restrict__ pf,      // [16][128][128]
    const float* __restrict__ wht_g,   // [16][128][128]
    const float* __restrict__ Gp_g,    // [16][128][256]
    const uint32_t* __restrict__ WrP,  // 8192 u32 load-linear
    const float* __restrict__ wrb,     // [128]
    const float* __restrict__ wew,     // [128]
    const float* __restrict__ web,     // [1]
    const uint32_t* __restrict__ WgP,  // 16384 u32 load-linear
    const uint32_t* __restrict__ WTP,  // 98304 u32 load-linear (24 chunks)
    const uint32_t* __restrict__ TAp,  // [16] x 16384 u32
    const uint32_t* __restrict__ DWp,  // [16] x 16384 u32
    const float* __restrict__ bbv,     // [512]
    float* __restrict__ out) {         // [16][128][128]
  const int b = blockIdx.x, t = threadIdx.x;

  __shared__ __align__(16) uint4 dwp_l[4096];     // 65536 B: whs fp16 (D)
  __shared__ __align__(16) uint4 lds_wt4[4096];   // 65536 B: WT chunks 0..3
  __shared__ __align__(16) uint32_t xh_h2[192];   // [xh;h] as half2 pairs
  __shared__ __align__(16) float tu_s[144];
  __shared__ __align__(16) float wew_s[144];
  __shared__ __align__(16) float sc_s[288];
  __shared__ __align__(16) float alpha_s[144];
  __shared__ __align__(16) float h_s[160];
  __shared__ __align__(16) float gates_s[512];

  const int jA = t >> 3, kgA = t & 7;   // A: 128 j x 8 kg (16 k)
  const int qB = t >> 2, hgB = t & 3;   // B: 256 q x 4 hg (32 h)
  const int hD = t >> 3, qgD = t & 7;   // D: 128 h x 8 qg (32 q interleaved)
  const int iE = t >> 2, kgE = t & 3;   // E: 256 i x 4 kg (32 k)
  const int iF = t >> 1, kgF = t & 1;   // F: 512 rows x 2 kg (192 k)

  const uint4* wrp4 = (const uint4*)WrP;                    // 2048 uint4
  const uint4* wgp4 = (const uint4*)WgP;                    // 4096 uint4
  const uint4* wtp4 = (const uint4*)WTP;                    // 24576 uint4
  const uint4* tap4 = (const uint4*)TAp + (size_t)b * 4096; // 4096 uint4
  const uint4* dwp4 = (const uint4*)DWp + (size_t)b * 4096; // 4096 uint4

  // ---- LDS init: whs-fp16 (D) + resident WT chunks 0..3 + small buffers
  for (int i = t; i < 4096; i += 1024) dwp_l[i] = dwp4[i];
  for (int i = t; i < 4096; i += 1024) lds_wt4[i] = wtp4[i];
  if (t < 128) wew_s[TUIDX(t)] = wew[t];
  if (t < 160) h_s[t] = 0.f;
  if (t < 64) xh_h2[128 + t] = 0u;      // h half2 part, step 0

  const float wrb_r = wrb[jA];
  const float web_r = web[0];
  const float bbF_r = bbv[iF];
  float c_r = 0.f;                       // t<128 owners

  // per-step prefetch registers (rotate)
  float wht_c = (kgA == 0) ? wht_g[((size_t)b * 128 + 0) * 128 + jA] : 0.f;
  float gp_c  = (kgE == 0) ? Gp_g[((size_t)b * 128 + 0) * 256 + iE] : 0.f;
  float pf_c  = (kgE == 0 && iE >= 128) ? pf[((size_t)b * 128 + 0) * 128 + (iE - 128)] : 0.f;

  __syncthreads();

  for (int st = 0; st < 128; st++) {
    const int st1 = (st < 127) ? st + 1 : 127;
    float wht_n = (kgA == 0) ? wht_g[((size_t)b * 128 + st1) * 128 + jA] : 0.f;
    float gp_n  = (kgE == 0) ? Gp_g[((size_t)b * 128 + st1) * 256 + iE] : 0.f;
    float pf_n  = (kgE == 0 && iE >= 128) ? pf[((size_t)b * 128 + st1) * 128 + (iE - 128)] : 0.f;

    // ---- A: tu = tanh(h@Wr^T + wrb + wht)   [2 coalesced uint4 loads]
    {
      float acc = 0.f;
#pragma unroll
      for (int i = 0; i < 2; i++) {
        uint4 wv = wrp4[i * 1024 + t];
        const float* hp = h_s + kgA * 20 + i * 8;
        float4 hA = *(const float4*)(hp);
        float4 hB = *(const float4*)(hp + 4);
        float2 w0 = h2f(wv.x), w1 = h2f(wv.y), w2 = h2f(wv.z), w3 = h2f(wv.w);
        acc = fmaf(hA.x, w0.x, acc); acc = fmaf(hA.y, w0.y, acc);
        acc = fmaf(hA.z, w1.x, acc); acc = fmaf(hA.w, w1.y, acc);
        acc = fmaf(hB.x, w2.x, acc); acc = fmaf(hB.y, w2.y, acc);
        acc = fmaf(hB.z, w3.x, acc); acc = fmaf(hB.w, w3.y, acc);
      }
      acc += __shfl_xor(acc, 1);
      acc += __shfl_xor(acc, 2);
      acc += __shfl_xor(acc, 4);
      if (kgA == 0) tu_s[TUIDX(jA)] = tanh_fast(acc + wrb_r + wht_c);
    }
    __syncthreads();

    // ---- B: sc[q] = sum_h we_h * (ta+tu)/(1+ta*tu)  [4 coalesced uint4]
    {
      float acc = 0.f;
#pragma unroll
      for (int i = 0; i < 4; i++) {
        uint4 av = tap4[i * 1024 + t];
        const float* up = tu_s + hgB * 36 + i * 8;
        const float* wp = wew_s + hgB * 36 + i * 8;
        float4 uA = *(const float4*)(up);
        float4 uB = *(const float4*)(up + 4);
        float4 wA = *(const float4*)(wp);
        float4 wB = *(const float4*)(wp + 4);
        float2 a0 = h2f(av.x), a1 = h2f(av.y), a2 = h2f(av.z), a3 = h2f(av.w);
        acc = fmaf((a0.x + uA.x) * frcp(fmaxf(fmaf(a0.x, uA.x, 1.f), 1e-6f)), wA.x, acc);
        acc = fmaf((a0.y + uA.y) * frcp(fmaxf(fmaf(a0.y, uA.y, 1.f), 1e-6f)), wA.y, acc);
        acc = fmaf((a1.x + uA.z) * frcp(fmaxf(fmaf(a1.x, uA.z, 1.f), 1e-6f)), wA.z, acc);
        acc = fmaf((a1.y + uA.w) * frcp(fmaxf(fmaf(a1.y, uA.w, 1.f), 1e-6f)), wA.w, acc);
        acc = fmaf((a2.x + uB.x) * frcp(fmaxf(fmaf(a2.x, uB.x, 1.f), 1e-6f)), wB.x, acc);
        acc = fmaf((a2.y + uB.y) * frcp(fmaxf(fmaf(a2.y, uB.y, 1.f), 1e-6f)), wB.y, acc);
        acc = fmaf((a3.x + uB.z) * frcp(fmaxf(fmaf(a3.x, uB.z, 1.f), 1e-6f)), wB.z, acc);
        acc = fmaf((a3.y + uB.w) * frcp(fmaxf(fmaf(a3.y, uB.w, 1.f), 1e-6f)), wB.w, acc);
      }
      acc += __shfl_xor(acc, 1);
      acc += __shfl_xor(acc, 2);
      if (hgB == 0) sc_s[SCIDX(qB)] = acc + web_r;
    }
    __syncthreads();

    // ---- D (softmax fused): per-lane max -> shfl(qgD bits) -> global mx;
    //      pass2: acc_w = sum e*whs (fp16 LDS), acc_e = sum e; alpha at end.
    {
      float mx = -3.4e38f;
#pragma unroll 8
      for (int r = 0; r < 32; r++)
        mx = fmaxf(mx, sc_s[SCIDX(qgD + 8 * r)]);
      mx = fmaxf(mx, __shfl_xor(mx, 1));
      mx = fmaxf(mx, __shfl_xor(mx, 2));
      mx = fmaxf(mx, __shfl_xor(mx, 4));
      float accw = 0.f, acce = 0.f;
#pragma unroll
      for (int i = 0; i < 4; i++) {
        uint4 v = dwp_l[i * 1024 + t];
        const int q00 = qgD + 64 * i;
#pragma unroll
        for (int w = 0; w < 4; w++) {
          uint32_t uw = (w == 0) ? v.x : (w == 1) ? v.y : (w == 2) ? v.z : v.w;
          float2 s = h2f(uw);
          int q0 = q00 + 16 * w;
          float e0 = __expf(sc_s[SCIDX(q0)] - mx);
          float e1 = __expf(sc_s[SCIDX(q0 + 8)] - mx);
          accw = fmaf(e0, s.x, fmaf(e1, s.y, accw));
          acce += e0 + e1;
        }
      }
      accw += __shfl_xor(accw, 1);
      accw += __shfl_xor(accw, 2);
      accw += __shfl_xor(accw, 4);
      acce += __shfl_xor(acce, 1);
      acce += __shfl_xor(acce, 2);
      acce += __shfl_xor(acce, 4);
      if (qgD == 0) alpha_s[AIDX(hD)] = accw * frcp(acce);
    }
    __syncthreads();

    // ---- E: gate = sigmoid(Wg[:,:128]@alpha + Gp); xh_h2 = pack(gate*[alpha;p])
    {
      float acc = 0.f;
#pragma unroll
      for (int i = 0; i < 4; i++) {
        uint4 wv = wgp4[i * 1024 + t];
        const float* ap = alpha_s + kgE * 36 + i * 8;
        float4 aA = *(const float4*)(ap);
        float4 aB = *(const float4*)(ap + 4);
        float2 w0 = h2f(wv.x), w1 = h2f(wv.y), w2 = h2f(wv.z), w3 = h2f(wv.w);
        acc = fmaf(aA.x, w0.x, acc); acc = fmaf(aA.y, w0.y, acc);
        acc = fmaf(aA.z, w1.x, acc); acc = fmaf(aA.w, w1.y, acc);
        acc = fmaf(aB.x, w2.x, acc); acc = fmaf(aB.y, w2.y, acc);
        acc = fmaf(aB.z, w3.x, acc); acc = fmaf(aB.w, w3.y, acc);
      }
      acc += __shfl_xor(acc, 1);
      acc += __shfl_xor(acc, 2);
      float v = 0.f;
      if (kgE == 0) {
        float sg = sigm(gp_c + acc);
        float xv = (iE < 128) ? alpha_s[AIDX(iE)] : pf_c;
        v = sg * xv;
      }
      float vp = __shfl_xor(v, 4);              // partner iE^1 (kgE==0 lanes)
      if (kgE == 0 && (iE & 1) == 0) xh_h2[iE >> 1] = f2h(v, vp);
    }
    __syncthreads();

    // ---- F: gates = WT@[xh;h] via dot2; chunks 0..3 LDS-resident,
    //      4..23 compiler-scheduled direct loads (320KB/step stream)
    {
      const uint4* xv4 = (const uint4*)xh_h2;   // 48 uint4 (broadcast reads)
      float acc = 0.f;
#pragma unroll
      for (int i = 0; i < 4; i++) {
        uint4 wv = lds_wt4[i * 1024 + t];
        uint4 xv = xv4[kgF * 24 + i];
        acc = dot2(wv.x, xv.x, acc); acc = dot2(wv.y, xv.y, acc);
        acc = dot2(wv.z, xv.z, acc); acc = dot2(wv.w, xv.w, acc);
      }
#pragma unroll 8
      for (int i = 4; i < 24; i++) {
        uint4 wv = wtp4[i * 1024 + t];
        uint4 xv = xv4[kgF * 24 + i];
        acc = dot2(wv.x, xv.x, acc); acc = dot2(wv.y, xv.y, acc);
        acc = dot2(wv.z, xv.z, acc); acc = dot2(wv.w, xv.w, acc);
      }
      acc += __shfl_xor(acc, 1);
      if (kgF == 0) gates_s[iF] = acc + bbF_r;
    }
    __syncthreads();

    // ---- cell: c in regs; h -> h_s fp32 + xh_h2 fp16 pairs; out (R15 verbatim)
    if (t < 128) {
      float iv = sigm(gates_s[t]);
      float fv = sigm(gates_s[128 + t]);
      float gv = tanh_fast(gates_s[256 + t]);
      float ov = sigm(gates_s[384 + t]);
      float cn = fmaf(fv, c_r, iv * gv);
      float hn = ov * tanh_fast(cn);
      c_r = cn;
      h_s[HIDX(t)] = hn;
      float hp = __shfl_xor(hn, 1);
      if ((t & 1) == 0) xh_h2[128 + (t >> 1)] = f2h(hn, hp);
      out[((size_t)b * 128 + st) * 128 + t] = hn;
    }
    __syncthreads();

    wht_c = wht_n; gp_c = gp_n; pf_c = pf_n;
  }
}

// ----------------------------------------------------------------- launcher
extern "C" void kernel_launch(void* const* d_in, const int* in_sizes, int n_in,
                              void* d_out, int out_size, void* d_ws, size_t ws_size,
                              hipStream_t stream) {
  static const int SZ_DICT[18] = {262144, 524288, 16384, 128, 16384, 128,
                                  16384, 128, 128, 1, 65536, 256,
                                  131072, 65536, 512, 512, 2048, 4096};
  static const int ALPHA2DICT[18] = {9, 8, 11, 10, 13, 12, 7, 6, 3, 2, 5, 4,
                                     15, 14, 0, 16, 1, 17};
  const void* in[18];
  for (int i = 0; i < 18; i++) in[i] = (i < n_in) ? d_in[i] : nullptr;

  bool dict_ok = true;
  int lim = (n_in < 16) ? n_in : 16;
  for (int i = 0; i < lim; i++) if (in_sizes[i] != SZ_DICT[i]) dict_ok = false;
  if (!dict_ok) {
    bool alpha_ok = true;
    for (int s = 0; s < n_in && s < 18; s++)
      if (in_sizes[s] != SZ_DICT[ALPHA2DICT[s]]) alpha_ok = false;
    if (alpha_ok)
      for (int s = 0; s < n_in && s < 18; s++) in[ALPHA2DICT[s]] = d_in[s];
  }

  const void* p   = in[0];  const void* q   = in[1];
  const void* Wsw = in[2];  const void* Wsb = in[3];
  const void* Wtw = in[4];  const void* Wtb = in[5];
  const void* Wrw = in[6];  const void* Wrb = in[7];
  const void* Wew = in[8];  const void* Web = in[9];
  const void* Wgw = in[10]; const void* Wgb = in[11];
  const void* Wih = in[12]; const void* Whh = in[13];
  const void* bih = in[14]; const void* bhh = in[15];

  float* ws = (float*)d_ws;
  float* whs  = ws;                          // 524288
  float* pff  = whs + 524288;                // 262144
  float* wht  = pff + 262144;                // 262144
  float* Gp   = wht + 262144;                // 524288
  uint32_t* WrP = (uint32_t*)(Gp + 524288);  // 8192
  uint32_t* WgP = WrP + 8192;                // 16384
  uint32_t* WTP = WgP + 16384;               // 98304
  uint32_t* TAp = WTP + 98304;               // 262144
  uint32_t* DWp = TAp + 262144;              // 262144
  float* bbv  = (float*)(DWp + 262144);      // 512
  float* wrb  = bbv + 512;                   // 128
  float* wew  = wrb + 128;                   // 128
  float* web  = wew + 128;                   // 4 (1 used)
  uint32_t* flag = (uint32_t*)(web + 4);     // 4     (~8.8 MB total)

  hipLaunchKernelGGL(detect_kernel, dim3(1), dim3(256), 0, stream,
                     (const uint16_t*)q, flag);
  // 385793 init elements -> 1508 blocks x 256
  hipLaunchKernelGGL(pack2, dim3(1508), dim3(256), 0, stream,
                     p, Wrw, Wrb, Wew, Web, Wgw, Wih, Whh, bih, bhh,
                     pff, WrP, wrb, wew, web, WgP, WTP, bbv, flag);
  hipLaunchKernelGGL(gemm3, dim3(512), dim3(256), 0, stream,
                     q, p, Wsw, Wsb, Wtw, Wtb, Wgw, Wgb, whs, wht, Gp, flag);
  // 524288 outputs -> 2048 blocks x 256
  hipLaunchKernelGGL(actpack, dim3(2048), dim3(256), 0, stream, whs, TAp, DWp);
  hipLaunchKernelGGL(mlstm_seq13, dim3(16), dim3(1024), 0, stream,
                     pff, wht, Gp, WrP, wrb, wew, web, WgP, WTP, TAp, DWp, bbv,
                     (float*)d_out);
}

// Round 15
// 1632.365 us; speedup vs baseline: 1.1409x; 1.1409x over previous
//
#include <hip/hip_runtime.h>
#include <hip/hip_fp16.h>
#include <cstdint>

// mLstm  B=16, P=128, Q=256, D=128, H=128. fp32 in/out.
// R20 = R18 with the ONE race fixed (R18 failed absmax 0.0638): the step
// counter was ctr[st] SHARED across all 16 batch groups -- any 4 blocks
// chip-wide opened every group's gate. Now ctr[16][128]: each group's leader
// adds/spins on its OWN ctr_b[st] (R7's proven per-batch pattern).
// Design (unchanged): R15 phases VERBATIM + 4-way split of ONLY F+cell across
// 64 blocks (4/batch, stride-16 grouping -> same XCD). A/B/C/D/E redundant.
// One handshake/step: cell publishes 32 h (agent store) -> leader release-add
// -> LEADER-ONLY acquire spin (R8 lesson) -> stage reads h[128].
// Per-block stream 544->256KB/step (F: 96KB slice).
// Init count: 385793+4096+2048 = 391937 -> 1532 blocks x 256 (R9 lesson).

__device__ __forceinline__ float bf2f(uint16_t u) {
  uint32_t x = ((uint32_t)u) << 16; float f; __builtin_memcpy(&f, &x, 4); return f;
}
__device__ __forceinline__ float load_in(const void* p, size_t i, int f32) {
  return f32 ? ((const float*)p)[i] : bf2f(((const uint16_t*)p)[i]);
}
__device__ __forceinline__ float frcp(float x) { return __builtin_amdgcn_rcpf(x); }
__device__ __forceinline__ float tanh_fast(float x) {
  float E = __expf(2.0f * x);
  return 1.0f - 2.0f * frcp(E + 1.0f);
}
__device__ __forceinline__ float sigm(float x) { return frcp(1.0f + __expf(-x)); }
__device__ __forceinline__ float2 h2f(uint32_t u) {
  __half2 h; __builtin_memcpy(&h, &u, 4); return __half22float2(h);
}
__device__ __forceinline__ uint32_t f2h(float a, float b) {
  __half2 h = __floats2half2_rn(a, b);
  uint32_t u; __builtin_memcpy(&u, &h, 4); return u;
}
__device__ __forceinline__ void st_agent(float* p, float v) {
  __hip_atomic_store(p, v, __ATOMIC_RELAXED, __HIP_MEMORY_SCOPE_AGENT);
}
__device__ __forceinline__ float ld_agent(const float* p) {
  return __hip_atomic_load(p, __ATOMIC_RELAXED, __HIP_MEMORY_SCOPE_AGENT);
}

typedef _Float16 h2v __attribute__((ext_vector_type(2)));
__device__ __forceinline__ float dot2(uint32_t w, uint32_t x, float acc) {
#if defined(__has_builtin)
#if __has_builtin(__builtin_amdgcn_fdot2)
  h2v a, b; __builtin_memcpy(&a, &w, 4); __builtin_memcpy(&b, &x, 4);
  return __builtin_amdgcn_fdot2(a, b, acc, false);
#else
  float2 af = h2f(w), bf = h2f(x);
  return fmaf(af.x, bf.x, fmaf(af.y, bf.y, acc));
#endif
#else
  float2 af = h2f(w), bf = h2f(x);
  return fmaf(af.x, bf.x, fmaf(af.y, bf.y, acc));
#endif
}

// ------------------------------------------------------------- detect kernel
__global__ void detect_kernel(const uint16_t* __restrict__ q16,
                              uint32_t* __restrict__ flag) {
  __shared__ int cnt;
  if (threadIdx.x == 0) cnt = 0;
  __syncthreads();
  int bad = 0;
  for (int i = threadIdx.x; i < 4096; i += 256) {
    int e = (q16[i] >> 7) & 0xFF;
    if (e > 0x8A) bad++;
  }
  atomicAdd(&cnt, bad);
  __syncthreads();
  if (threadIdx.x == 0) *flag = (cnt > 16) ? 1u : 0u;
}

// ------------------------------------------------- convert + pack
// WTPs (slice pack): u32 idx: c=idx>>2; w=idx&3; C=c>>10 (0..23); t=c&1023;
//   slice=C/6; i=C%6; iF2=t>>3; kgF2=t&7; gate=iF2>>5; hl=iF2&31;
//   row=gate*128+slice*32+hl; k=kgF2*48+i*8+w*2;
//   val = half2(WT[k][row], WT[k+1][row]); WT[k]=k<256?Wih[:,k]:Whh[:,k-256].
// WrP/WgP/pf/TAp unchanged (R12/R15). Appended: zero h_ex[4096], ctr[2048].
// Total 262144+8192+128+128+1+16384+98304+512+4096+2048 = 391937 -> 1532 x 256.
__global__ void pack2(const void* __restrict__ p,
                      const void* __restrict__ Wr,  const void* __restrict__ Wrb_,
                      const void* __restrict__ Wew_, const void* __restrict__ Web_,
                      const void* __restrict__ Wg,
                      const void* __restrict__ Wih, const void* __restrict__ Whh,
                      const void* __restrict__ bih, const void* __restrict__ bhh,
                      float* __restrict__ pf,
                      uint32_t* __restrict__ WrP, float* __restrict__ wrb,
                      float* __restrict__ wew, float* __restrict__ web,
                      uint32_t* __restrict__ WgP, uint32_t* __restrict__ WTPs,
                      float* __restrict__ bbv,
                      const uint32_t* __restrict__ flag,
                      float* __restrict__ hexz, uint32_t* __restrict__ ctrz) {
  const int f32 = (int)*flag;
  long idx = (long)blockIdx.x * blockDim.x + threadIdx.x;
  if (idx < 262144) { pf[idx] = load_in(p, idx, f32); return; }
  idx -= 262144;
  if (idx < 8192) {
    int c = (int)(idx >> 2), w = (int)(idx & 3);
    int i = c >> 10, t = c & 1023;
    int jA = t >> 3, kgA = t & 7;
    int k = kgA * 16 + i * 8 + w * 2;
    WrP[idx] = f2h(load_in(Wr, (size_t)jA * 128 + k, f32),
                   load_in(Wr, (size_t)jA * 128 + k + 1, f32));
    return; }
  idx -= 8192;
  if (idx < 128) { wrb[idx] = load_in(Wrb_, idx, f32); return; }
  idx -= 128;
  if (idx < 128) { wew[idx] = load_in(Wew_, idx, f32); return; }
  idx -= 128;
  if (idx < 1) { web[0] = load_in(Web_, 0, f32); return; }
  idx -= 1;
  if (idx < 16384) {
    int c = (int)(idx >> 2), w = (int)(idx & 3);
    int i = c >> 10, t = c & 1023;
    int iE = t >> 2, kgE = t & 3;
    int k = kgE * 32 + i * 8 + w * 2;
    WgP[idx] = f2h(load_in(Wg, (size_t)iE * 256 + k, f32),
                   load_in(Wg, (size_t)iE * 256 + k + 1, f32));
    return; }
  idx -= 16384;
  if (idx < 98304) {
    int c = (int)(idx >> 2), w = (int)(idx & 3);
    int C = c >> 10, t = c & 1023;
    int slice = C / 6, i = C % 6;
    int iF2 = t >> 3, kgF2 = t & 7;
    int gate = iF2 >> 5, hl = iF2 & 31;
    int row = gate * 128 + slice * 32 + hl;
    int k = kgF2 * 48 + i * 8 + w * 2;
    float v0 = (k < 256) ? load_in(Wih, (size_t)row * 256 + k, f32)
                         : load_in(Whh, (size_t)row * 128 + (k - 256), f32);
    float v1 = (k + 1 < 256) ? load_in(Wih, (size_t)row * 256 + k + 1, f32)
                             : load_in(Whh, (size_t)row * 128 + (k + 1 - 256), f32);
    WTPs[idx] = f2h(v0, v1);
    return; }
  idx -= 98304;
  if (idx < 512) { bbv[idx] = load_in(bih, idx, f32) + load_in(bhh, idx, f32); return; }
  idx -= 512;
  if (idx < 4096) { hexz[idx] = 0.f; return; }
  idx -= 4096;
  if (idx < 2048) { ctrz[idx] = 0u; }
}

// --------------------------------------------- fused 3-way small GEMM (K=128)
__global__ __launch_bounds__(256) void gemm3(
    const void* __restrict__ q, const void* __restrict__ p,
    const void* __restrict__ Wsw, const void* __restrict__ Wsb,
    const void* __restrict__ Wtw, const void* __restrict__ Wtb,
    const void* __restrict__ Wgw, const void* __restrict__ Wgb,
    float* __restrict__ whs, float* __restrict__ wht, float* __restrict__ Gp,
    const uint32_t* __restrict__ flag) {
  __shared__ float A_l[16][128];
  __shared__ float W_l[64][129];
  const int f32 = (int)*flag;
  const int t = threadIdx.x;
  const void* A; const void* W; const void* bias; float* out;
  int lda = 128, ldw, w_off, C, r0;
  int blk = blockIdx.x;
  if (blk < 256)      { A = q; W = Wsw; bias = Wsb; out = whs; ldw = 128; w_off = 0;   C = 128; r0 = blk * 16; }
  else if (blk < 384) { A = p; W = Wtw; bias = Wtb; out = wht; ldw = 128; w_off = 0;   C = 128; r0 = (blk - 256) * 16; }
  else                { A = p; W = Wgw; bias = Wgb; out = Gp;  ldw = 256; w_off = 128; C = 256; r0 = (blk - 384) * 16; }
  for (int idx = t; idx < 16 * 128; idx += 256) {
    int rr = idx >> 7, kk = idx & 127;
    A_l[rr][kk] = load_in(A, (size_t)(r0 + rr) * lda + kk, f32);
  }
  const int c_l = t & 63, rg = t >> 6;
  for (int c0 = 0; c0 < C; c0 += 64) {
    __syncthreads();
    for (int idx = t; idx < 64 * 128; idx += 256) {
      int cc = idx >> 7, kk = idx & 127;
      W_l[cc][kk] = load_in(W, (size_t)w_off + (size_t)(c0 + cc) * ldw + kk, f32);
    }
    __syncthreads();
    float acc[4] = {0.f, 0.f, 0.f, 0.f};
    for (int k = 0; k < 128; k++) {
      float w = W_l[c_l][k];
#pragma unroll
      for (int x = 0; x < 4; x++) acc[x] = fmaf(A_l[rg * 4 + x][k], w, acc[x]);
    }
    float bv = load_in(bias, c0 + c_l, f32);
#pragma unroll
    for (int x = 0; x < 4; x++)
      out[(size_t)(r0 + rg * 4 + x) * C + c0 + c_l] = acc[x] + bv;
  }
}

// --------------------------- tA = tanh(whs) as fp16, per-thread load-linear
// (R12/R15 verbatim) 262144 u32 -> 1024 blocks x 256.
__global__ void tapack(const float* __restrict__ whs, uint32_t* __restrict__ TAp) {
  int o = blockIdx.x * 256 + threadIdx.x;
  int b = o >> 14, r = o & 16383;
  int c = r >> 2, w = r & 3;
  int i = c >> 10, t = c & 1023;
  int qB = t >> 2, hgB = t & 3;
  int h = hgB * 32 + i * 8 + w * 2;
  const float* base = whs + ((size_t)b * 256 + qB) * 128 + h;
  TAp[o] = f2h(tanhf(base[0]), tanhf(base[1]));
}

// ---------------------------------------------------------- sequential kernel
#define TUIDX(j) ((((j) >> 5) * 36) + ((j) & 31))
#define SCIDX(q) ((((q) >> 5) * 36) + ((q) & 31))
#define AIDX(h)  ((((h) >> 5) * 36) + ((h) & 31))
#define HIDX(k)  ((((k) >> 4) * 20) + ((k) & 15))

__global__ __launch_bounds__(1024) void mlstm_seq15(
    const float* __restrict__ pf,      // [16][128][128]
    const float* __restrict__ whs,     // [16][256][128]
    const float* __restrict__ wht_g,   // [16][128][128]
    const float* __restrict__ Gp_g,    // [16][128][256]
    const uint32_t* __restrict__ WrP,  // 8192 u32 load-linear
    const float* __restrict__ wrb,     // [128]
    const float* __restrict__ wew,     // [128]
    const float* __restrict__ web,     // [1]
    const uint32_t* __restrict__ WgP,  // 16384 u32 load-linear
    const uint32_t* __restrict__ WTPs, // 98304 u32 slice-packed
    const uint32_t* __restrict__ TAp,  // [16] x 16384 u32
    const float* __restrict__ bbv,     // [512]
    float* __restrict__ h_ex,          // [2][16][128] parity exchange
    uint32_t* __restrict__ ctr,        // [16][128] PER-BATCH counters (R20 fix)
    float* __restrict__ out) {         // [16][128][128]
  const int b = blockIdx.x & 15, slice = blockIdx.x >> 4, t = threadIdx.x;

  __shared__ __align__(16) float whs_l[256 * 132];   // 135168 B padded rows
  __shared__ __align__(16) uint32_t xh_h2[192];      // [xh;h] as half2 pairs
  __shared__ __align__(16) float tu_s[144];
  __shared__ __align__(16) float wew_s[144];
  __shared__ __align__(16) float sc_s[288];
  __shared__ __align__(16) float e_s[256];
  __shared__ __align__(16) float alpha_s[144];
  __shared__ __align__(16) float h_s[160];
  __shared__ __align__(16) float gates_s[128];
  __shared__ float inv_s;

  const float* whs_b = whs + (size_t)b * 32768;

  const int jA = t >> 3, kgA = t & 7;   // A: 128 j x 8 kg (16 k)
  const int qB = t >> 2, hgB = t & 3;   // B: 256 q x 4 hg (32 h)
  const int hD = t >> 3, qgD = t & 7;   // D: 128 h x 8 qg (32 q interleaved)
  const int iE = t >> 2, kgE = t & 3;   // E: 256 i x 4 kg (32 k)
  const int iF2 = t >> 3, kgF2 = t & 7; // F: 128 slice-rows x 8 kg (48 k)

  // ---- LDS init: whs fp32 padded rows (for D); small buffers
  for (int i4 = t; i4 < 8192; i4 += 1024)
    *(float4*)(whs_l + (i4 >> 5) * 132 + ((i4 & 31) << 2)) =
        *(const float4*)(whs_b + ((size_t)i4 << 2));
  if (t < 128) wew_s[TUIDX(t)] = wew[t];
  if (t < 160) h_s[t] = 0.f;
  if (t < 64) xh_h2[128 + t] = 0u;      // h half2 part, step 0

  const float wrb_r = wrb[jA];
  const float web_r = web[0];
  const float bbF_r = bbv[(iF2 >> 5) * 128 + slice * 32 + (iF2 & 31)];
  float c_r = 0.f;                       // owners t<32 (h = slice*32+t)

  const uint4* wrp4 = (const uint4*)WrP;                    // 2048 uint4
  const uint4* wgp4 = (const uint4*)WgP;                    // 4096 uint4
  const uint4* wts4 = (const uint4*)WTPs + (size_t)(slice * 6) * 1024; // 6144
  const uint4* tap4 = (const uint4*)TAp + (size_t)b * 4096; // 4096 uint4
  uint32_t* ctr_b = ctr + b * 128;      // R20 fix: per-batch counter row

  // per-step prefetch registers (rotate)
  float wht_c = (kgA == 0) ? wht_g[((size_t)b * 128 + 0) * 128 + jA] : 0.f;
  float gp_c  = (kgE == 0) ? Gp_g[((size_t)b * 128 + 0) * 256 + iE] : 0.f;
  float pf_c  = (kgE == 0 && iE >= 128) ? pf[((size_t)b * 128 + 0) * 128 + (iE - 128)] : 0.f;

  __syncthreads();

  for (int st = 0; st < 128; st++) {
    const int st1 = (st < 127) ? st + 1 : 127;
    float wht_n = (kgA == 0) ? wht_g[((size_t)b * 128 + st1) * 128 + jA] : 0.f;
    float gp_n  = (kgE == 0) ? Gp_g[((size_t)b * 128 + st1) * 256 + iE] : 0.f;
    float pf_n  = (kgE == 0 && iE >= 128) ? pf[((size_t)b * 128 + st1) * 128 + (iE - 128)] : 0.f;

    // ---- A: tu = tanh(h@Wr^T + wrb + wht)   [R15 verbatim]
    {
      float acc = 0.f;
#pragma unroll
      for (int i = 0; i < 2; i++) {
        uint4 wv = wrp4[i * 1024 + t];
        const float* hp = h_s + kgA * 20 + i * 8;
        float4 hA = *(const float4*)(hp);
        float4 hB = *(const float4*)(hp + 4);
        float2 w0 = h2f(wv.x), w1 = h2f(wv.y), w2 = h2f(wv.z), w3 = h2f(wv.w);
        acc = fmaf(hA.x, w0.x, acc); acc = fmaf(hA.y, w0.y, acc);
        acc = fmaf(hA.z, w1.x, acc); acc = fmaf(hA.w, w1.y, acc);
        acc = fmaf(hB.x, w2.x, acc); acc = fmaf(hB.y, w2.y, acc);
        acc = fmaf(hB.z, w3.x, acc); acc = fmaf(hB.w, w3.y, acc);
      }
      acc += __shfl_xor(acc, 1);
      acc += __shfl_xor(acc, 2);
      acc += __shfl_xor(acc, 4);
      if (kgA == 0) tu_s[TUIDX(jA)] = tanh_fast(acc + wrb_r + wht_c);
    }
    __syncthreads();

    // ---- B: sc[q] = sum_h we_h * (ta+tu)/(1+ta*tu)   [R15 verbatim]
    {
      float acc = 0.f;
#pragma unroll
      for (int i = 0; i < 4; i++) {
        uint4 av = tap4[i * 1024 + t];
        const float* up = tu_s + hgB * 36 + i * 8;
        const float* wp = wew_s + hgB * 36 + i * 8;
        float4 uA = *(const float4*)(up);
        float4 uB = *(const float4*)(up + 4);
        float4 wA = *(const float4*)(wp);
        float4 wB = *(const float4*)(wp + 4);
        float2 a0 = h2f(av.x), a1 = h2f(av.y), a2 = h2f(av.z), a3 = h2f(av.w);
        acc = fmaf((a0.x + uA.x) * frcp(fmaxf(fmaf(a0.x, uA.x, 1.f), 1e-6f)), wA.x, acc);
        acc = fmaf((a0.y + uA.y) * frcp(fmaxf(fmaf(a0.y, uA.y, 1.f), 1e-6f)), wA.y, acc);
        acc = fmaf((a1.x + uA.z) * frcp(fmaxf(fmaf(a1.x, uA.z, 1.f), 1e-6f)), wA.z, acc);
        acc = fmaf((a1.y + uA.w) * frcp(fmaxf(fmaf(a1.y, uA.w, 1.f), 1e-6f)), wA.w, acc);
        acc = fmaf((a2.x + uB.x) * frcp(fmaxf(fmaf(a2.x, uB.x, 1.f), 1e-6f)), wB.x, acc);
        acc = fmaf((a2.y + uB.y) * frcp(fmaxf(fmaf(a2.y, uB.y, 1.f), 1e-6f)), wB.y, acc);
        acc = fmaf((a3.x + uB.z) * frcp(fmaxf(fmaf(a3.x, uB.z, 1.f), 1e-6f)), wB.z, acc);
        acc = fmaf((a3.y + uB.w) * frcp(fmaxf(fmaf(a3.y, uB.w, 1.f), 1e-6f)), wB.w, acc);
      }
      acc += __shfl_xor(acc, 1);
      acc += __shfl_xor(acc, 2);
      if (hgB == 0) sc_s[SCIDX(qB)] = acc + web_r;
    }
    __syncthreads();

    // ---- C: softmax stats + e_s (wave 0)   [R15 verbatim]
    if (t < 64) {
      float s0 = sc_s[SCIDX(t)],       s1 = sc_s[SCIDX(t + 64)];
      float s2 = sc_s[SCIDX(t + 128)], s3 = sc_s[SCIDX(t + 192)];
      float mx = fmaxf(fmaxf(s0, s1), fmaxf(s2, s3));
#pragma unroll
      for (int d = 1; d < 64; d <<= 1) mx = fmaxf(mx, __shfl_xor(mx, d));
      float e0 = __expf(s0 - mx), e1 = __expf(s1 - mx),
            e2 = __expf(s2 - mx), e3 = __expf(s3 - mx);
      float sum = e0 + e1 + e2 + e3;
#pragma unroll
      for (int d = 1; d < 64; d <<= 1) sum += __shfl_xor(sum, d);
      e_s[t] = e0; e_s[t + 64] = e1; e_s[t + 128] = e2; e_s[t + 192] = e3;
      if (t == 0) inv_s = frcp(sum);
    }
    __syncthreads();

    // ---- D: alpha = (sum_q e[q]*whs[q][h]) * inv   [R15 verbatim]
    {
      const float* whs_p = whs_l + qgD * 132 + hD;
      float acc = 0.f;
#pragma unroll 8
      for (int r = 0; r < 32; r++)        // q = qgD + 8r
        acc = fmaf(e_s[qgD + 8 * r], whs_p[r * 1056], acc);
      acc += __shfl_xor(acc, 1);
      acc += __shfl_xor(acc, 2);
      acc += __shfl_xor(acc, 4);
      if (qgD == 0) alpha_s[AIDX(hD)] = acc * inv_s;
    }
    __syncthreads();

    // ---- E: gate = sigmoid(Wg[:,:128]@alpha + Gp); xh_h2 pack  [R15 verbatim]
    {
      float acc = 0.f;
#pragma unroll
      for (int i = 0; i < 4; i++) {
        uint4 wv = wgp4[i * 1024 + t];
        const float* ap = alpha_s + kgE * 36 + i * 8;
        float4 aA = *(const float4*)(ap);
        float4 aB = *(const float4*)(ap + 4);
        float2 w0 = h2f(wv.x), w1 = h2f(wv.y), w2 = h2f(wv.z), w3 = h2f(wv.w);
        acc = fmaf(aA.x, w0.x, acc); acc = fmaf(aA.y, w0.y, acc);
        acc = fmaf(aA.z, w1.x, acc); acc = fmaf(aA.w, w1.y, acc);
        acc = fmaf(aB.x, w2.x, acc); acc = fmaf(aB.y, w2.y, acc);
        acc = fmaf(aB.z, w3.x, acc); acc = fmaf(aB.w, w3.y, acc);
      }
      acc += __shfl_xor(acc, 1);
      acc += __shfl_xor(acc, 2);
      float v = 0.f;
      if (kgE == 0) {
        float sg = sigm(gp_c + acc);
        float xv = (iE < 128) ? alpha_s[AIDX(iE)] : pf_c;
        v = sg * xv;
      }
      float vp = __shfl_xor(v, 4);              // partner iE^1 (kgE==0 lanes)
      if (kgE == 0 && (iE & 1) == 0) xh_h2[iE >> 1] = f2h(v, vp);
    }
    __syncthreads();

    // ---- F (slice): 128 rows x 48-k groups via dot2, 6 chunks (96KB stream)
    {
      const uint4* xv4 = (const uint4*)xh_h2;   // 48 uint4
      float acc = 0.f;
#pragma unroll
      for (int i = 0; i < 6; i++) {
        uint4 wv = wts4[i * 1024 + t];
        uint4 xv = xv4[kgF2 * 6 + i];
        acc = dot2(wv.x, xv.x, acc); acc = dot2(wv.y, xv.y, acc);
        acc = dot2(wv.z, xv.z, acc); acc = dot2(wv.w, xv.w, acc);
      }
      acc += __shfl_xor(acc, 1);
      acc += __shfl_xor(acc, 2);
      acc += __shfl_xor(acc, 4);
      if (kgF2 == 0) gates_s[iF2] = acc + bbF_r;
    }
    __syncthreads();

    // ---- cell (slice): h = slice*32+t for t<32; publish to h_ex + out
    if (t < 32) {
      float iv = sigm(gates_s[t]);
      float fv = sigm(gates_s[32 + t]);
      float gv = tanh_fast(gates_s[64 + t]);
      float ov = sigm(gates_s[96 + t]);
      float cn = fmaf(fv, c_r, iv * gv);
      float hn = ov * tanh_fast(cn);
      c_r = cn;
      int h = slice * 32 + t;
      st_agent(h_ex + ((st + 1) & 1) * 2048 + b * 128 + h, hn);
      out[((size_t)b * 128 + st) * 128 + h] = hn;
    }
    __syncthreads();                           // drain h stores (vmcnt->L2)
    if (t == 0)
      __hip_atomic_fetch_add(ctr_b + st, 1u, __ATOMIC_RELEASE,
                             __HIP_MEMORY_SCOPE_AGENT);
    if (st < 127) {
      if (t == 0) {                            // leader-only spin (R8 lesson)
        while (__hip_atomic_load(ctr_b + st, __ATOMIC_ACQUIRE,
                                 __HIP_MEMORY_SCOPE_AGENT) < 4u)
          __builtin_amdgcn_s_sleep(1);
      }
      __syncthreads();
      // ---- stage: read full h[128]; h_s + xh_h2 pack
      if (t < 128) {
        float hv = ld_agent(h_ex + ((st + 1) & 1) * 2048 + b * 128 + t);
        h_s[HIDX(t)] = hv;
        float hp = __shfl_xor(hv, 1);
        if ((t & 1) == 0) xh_h2[128 + (t >> 1)] = f2h(hv, hp);
      }
      __syncthreads();
    }
    wht_c = wht_n; gp_c = gp_n; pf_c = pf_n;
  }
}

// ----------------------------------------------------------------- launcher
extern "C" void kernel_launch(void* const* d_in, const int* in_sizes, int n_in,
                              void* d_out, int out_size, void* d_ws, size_t ws_size,
                              hipStream_t stream) {
  static const int SZ_DICT[18] = {262144, 524288, 16384, 128, 16384, 128,
                                  16384, 128, 128, 1, 65536, 256,
                                  131072, 65536, 512, 512, 2048, 4096};
  static const int ALPHA2DICT[18] = {9, 8, 11, 10, 13, 12, 7, 6, 3, 2, 5, 4,
                                     15, 14, 0, 16, 1, 17};
  const void* in[18];
  for (int i = 0; i < 18; i++) in[i] = (i < n_in) ? d_in[i] : nullptr;

  bool dict_ok = true;
  int lim = (n_in < 16) ? n_in : 16;
  for (int i = 0; i < lim; i++) if (in_sizes[i] != SZ_DICT[i]) dict_ok = false;
  if (!dict_ok) {
    bool alpha_ok = true;
    for (int s = 0; s < n_in && s < 18; s++)
      if (in_sizes[s] != SZ_DICT[ALPHA2DICT[s]]) alpha_ok = false;
    if (alpha_ok)
      for (int s = 0; s < n_in && s < 18; s++) in[ALPHA2DICT[s]] = d_in[s];
  }

  const void* p   = in[0];  const void* q   = in[1];
  const void* Wsw = in[2];  const void* Wsb = in[3];
  const void* Wtw = in[4];  const void* Wtb = in[5];
  const void* Wrw = in[6];  const void* Wrb = in[7];
  const void* Wew = in[8];  const void* Web = in[9];
  const void* Wgw = in[10]; const void* Wgb = in[11];
  const void* Wih = in[12]; const void* Whh = in[13];
  const void* bih = in[14]; const void* bhh = in[15];

  float* ws = (float*)d_ws;
  float* whs  = ws;                          // 524288
  float* pff  = whs + 524288;                // 262144
  float* wht  = pff + 262144;                // 262144
  float* Gp   = wht + 262144;                // 524288
  uint32_t* WrP = (uint32_t*)(Gp + 524288);  // 8192
  uint32_t* WgP = WrP + 8192;                // 16384
  uint32_t* WTPs = WgP + 16384;              // 98304
  uint32_t* TAp = WTPs + 98304;              // 262144
  float* bbv  = (float*)(TAp + 262144);      // 512
  float* wrb  = bbv + 512;                   // 128
  float* wew  = wrb + 128;                   // 128
  float* web  = wew + 128;                   // 4 (1 used)
  uint32_t* flag = (uint32_t*)(web + 4);     // 4
  float* h_ex = (float*)(flag + 4);          // 4096 (2 parity x 16 x 128)
  uint32_t* ctrp = (uint32_t*)(h_ex + 4096); // 2048 (16 x 128)  ~7.8 MB total

  hipLaunchKernelGGL(detect_kernel, dim3(1), dim3(256), 0, stream,
                     (const uint16_t*)q, flag);
  // 391937 init elements -> 1532 blocks x 256 (R20: per-batch ctr zeroing)
  hipLaunchKernelGGL(pack2, dim3(1532), dim3(256), 0, stream,
                     p, Wrw, Wrb, Wew, Web, Wgw, Wih, Whh, bih, bhh,
                     pff, WrP, wrb, wew, web, WgP, WTPs, bbv, flag,
                     h_ex, ctrp);
  hipLaunchKernelGGL(gemm3, dim3(512), dim3(256), 0, stream,
                     q, p, Wsw, Wsb, Wtw, Wtb, Wgw, Wgb, whs, wht, Gp, flag);
  hipLaunchKernelGGL(tapack, dim3(1024), dim3(256), 0, stream, whs, TAp);

  float* outf = (float*)d_out;
  const float* a0 = pff;  const float* a1 = whs;  const float* a2 = wht;
  const float* a3 = Gp;
  const uint32_t* a4 = WrP; const float* a5 = wrb; const float* a6 = wew;
  const float* a7 = web;  const uint32_t* a8 = WgP;
  const uint32_t* a9 = WTPs; const uint32_t* a10 = TAp;
  const float* a11 = bbv; float* a12 = h_ex; uint32_t* a13 = ctrp;
  float* a14 = outf;
  void* kargs[15] = {
    (void*)&a0, (void*)&a1, (void*)&a2, (void*)&a3, (void*)&a4,
    (void*)&a5, (void*)&a6, (void*)&a7, (void*)&a8, (void*)&a9,
    (void*)&a10, (void*)&a11, (void*)&a12, (void*)&a13, (void*)&a14
  };
  hipLaunchCooperativeKernel((const void*)mlstm_seq15, dim3(64), dim3(1024),
                             kargs, 0, stream);
}

// Round 16
// 1220.019 us; speedup vs baseline: 1.5265x; 1.3380x over previous
//
#include <hip/hip_runtime.h>
#include <hip/hip_fp16.h>
#include <cstdint>

// mLstm  B=16, P=128, Q=256, D=128, H=128. fp32 in/out.
// R21 = R15 (best measured: 1270us seq / 1410 total) + per-batch-constant
// LDS residency, built ONLY from individually-proven parts:
//  - tA (64KB fp16) copied to LDS once; B reads tap_l (same indices as the
//    proven global path; linear uint4, conflict-free like R17's dwp_l).
//  - whs held as fp16 dwp_l in LDS; D is R16's PASSED code with the pointer
//    swapped global->LDS (R16 absmax 1.953e-3).
//  - A/C/E/F/cell/pack layouts/7 barriers: R15 VERBATIM.
// Global stream 544->480KB/step; B and D fully LDS-fed (2x BW, no phase-start
// L2 latency). LDS 138KB. Cross-block splits CLOSED (R7/R10/R20: handshake
// >= 2-3.5us/step > any stream saving). No reg-resident weights (R6/R7/R13).

__device__ __forceinline__ float bf2f(uint16_t u) {
  uint32_t x = ((uint32_t)u) << 16; float f; __builtin_memcpy(&f, &x, 4); return f;
}
__device__ __forceinline__ float load_in(const void* p, size_t i, int f32) {
  return f32 ? ((const float*)p)[i] : bf2f(((const uint16_t*)p)[i]);
}
__device__ __forceinline__ float frcp(float x) { return __builtin_amdgcn_rcpf(x); }
__device__ __forceinline__ float tanh_fast(float x) {
  float E = __expf(2.0f * x);
  return 1.0f - 2.0f * frcp(E + 1.0f);
}
__device__ __forceinline__ float sigm(float x) { return frcp(1.0f + __expf(-x)); }
__device__ __forceinline__ float2 h2f(uint32_t u) {
  __half2 h; __builtin_memcpy(&h, &u, 4); return __half22float2(h);
}
__device__ __forceinline__ uint32_t f2h(float a, float b) {
  __half2 h = __floats2half2_rn(a, b);
  uint32_t u; __builtin_memcpy(&u, &h, 4); return u;
}

typedef _Float16 h2v __attribute__((ext_vector_type(2)));
__device__ __forceinline__ float dot2(uint32_t w, uint32_t x, float acc) {
#if defined(__has_builtin)
#if __has_builtin(__builtin_amdgcn_fdot2)
  h2v a, b; __builtin_memcpy(&a, &w, 4); __builtin_memcpy(&b, &x, 4);
  return __builtin_amdgcn_fdot2(a, b, acc, false);
#else
  float2 af = h2f(w), bf = h2f(x);
  return fmaf(af.x, bf.x, fmaf(af.y, bf.y, acc));
#endif
#else
  float2 af = h2f(w), bf = h2f(x);
  return fmaf(af.x, bf.x, fmaf(af.y, bf.y, acc));
#endif
}

// ------------------------------------------------------------- detect kernel
__global__ void detect_kernel(const uint16_t* __restrict__ q16,
                              uint32_t* __restrict__ flag) {
  __shared__ int cnt;
  if (threadIdx.x == 0) cnt = 0;
  __syncthreads();
  int bad = 0;
  for (int i = threadIdx.x; i < 4096; i += 256) {
    int e = (q16[i] >> 7) & 0xFF;
    if (e > 0x8A) bad++;
  }
  atomicAdd(&cnt, bad);
  __syncthreads();
  if (threadIdx.x == 0) *flag = (cnt > 16) ? 1u : 0u;
}

// ------------------------------------------------- convert + pack (R15 verbatim)
// Total 262144+8192+128+128+1+16384+98304+512 = 385793 -> grid 1508 x 256.
__global__ void pack2(const void* __restrict__ p,
                      const void* __restrict__ Wr,  const void* __restrict__ Wrb_,
                      const void* __restrict__ Wew_, const void* __restrict__ Web_,
                      const void* __restrict__ Wg,
                      const void* __restrict__ Wih, const void* __restrict__ Whh,
                      const void* __restrict__ bih, const void* __restrict__ bhh,
                      float* __restrict__ pf,
                      uint32_t* __restrict__ WrP, float* __restrict__ wrb,
                      float* __restrict__ wew, float* __restrict__ web,
                      uint32_t* __restrict__ WgP, uint32_t* __restrict__ WTP,
                      float* __restrict__ bbv,
                      const uint32_t* __restrict__ flag) {
  const int f32 = (int)*flag;
  long idx = (long)blockIdx.x * blockDim.x + threadIdx.x;
  if (idx < 262144) { pf[idx] = load_in(p, idx, f32); return; }
  idx -= 262144;
  if (idx < 8192) {
    int c = (int)(idx >> 2), w = (int)(idx & 3);
    int i = c >> 10, t = c & 1023;
    int jA = t >> 3, kgA = t & 7;
    int k = kgA * 16 + i * 8 + w * 2;
    WrP[idx] = f2h(load_in(Wr, (size_t)jA * 128 + k, f32),
                   load_in(Wr, (size_t)jA * 128 + k + 1, f32));
    return; }
  idx -= 8192;
  if (idx < 128) { wrb[idx] = load_in(Wrb_, idx, f32); return; }
  idx -= 128;
  if (idx < 128) { wew[idx] = load_in(Wew_, idx, f32); return; }
  idx -= 128;
  if (idx < 1) { web[0] = load_in(Web_, 0, f32); return; }
  idx -= 1;
  if (idx < 16384) {
    int c = (int)(idx >> 2), w = (int)(idx & 3);
    int i = c >> 10, t = c & 1023;
    int iE = t >> 2, kgE = t & 3;
    int k = kgE * 32 + i * 8 + w * 2;
    WgP[idx] = f2h(load_in(Wg, (size_t)iE * 256 + k, f32),
                   load_in(Wg, (size_t)iE * 256 + k + 1, f32));
    return; }
  idx -= 16384;
  if (idx < 98304) {
    int c = (int)(idx >> 2), w = (int)(idx & 3);
    int i = c >> 10, t = c & 1023;
    int iF = t >> 1, kgF = t & 1;
    int k = kgF * 192 + i * 8 + w * 2;
    float v0 = (k < 256) ? load_in(Wih, (size_t)iF * 256 + k, f32)
                         : load_in(Whh, (size_t)iF * 128 + (k - 256), f32);
    float v1 = (k + 1 < 256) ? load_in(Wih, (size_t)iF * 256 + k + 1, f32)
                             : load_in(Whh, (size_t)iF * 128 + (k + 1 - 256), f32);
    WTP[idx] = f2h(v0, v1);
    return; }
  idx -= 98304;
  if (idx < 512) { bbv[idx] = load_in(bih, idx, f32) + load_in(bhh, idx, f32); }
}

// --------------------------------------------- fused 3-way small GEMM (K=128)
__global__ __launch_bounds__(256) void gemm3(
    const void* __restrict__ q, const void* __restrict__ p,
    const void* __restrict__ Wsw, const void* __restrict__ Wsb,
    const void* __restrict__ Wtw, const void* __restrict__ Wtb,
    const void* __restrict__ Wgw, const void* __restrict__ Wgb,
    float* __restrict__ whs, float* __restrict__ wht, float* __restrict__ Gp,
    const uint32_t* __restrict__ flag) {
  __shared__ float A_l[16][128];
  __shared__ float W_l[64][129];
  const int f32 = (int)*flag;
  const int t = threadIdx.x;
  const void* A; const void* W; const void* bias; float* out;
  int lda = 128, ldw, w_off, C, r0;
  int blk = blockIdx.x;
  if (blk < 256)      { A = q; W = Wsw; bias = Wsb; out = whs; ldw = 128; w_off = 0;   C = 128; r0 = blk * 16; }
  else if (blk < 384) { A = p; W = Wtw; bias = Wtb; out = wht; ldw = 128; w_off = 0;   C = 128; r0 = (blk - 256) * 16; }
  else                { A = p; W = Wgw; bias = Wgb; out = Gp;  ldw = 256; w_off = 128; C = 256; r0 = (blk - 384) * 16; }
  for (int idx = t; idx < 16 * 128; idx += 256) {
    int rr = idx >> 7, kk = idx & 127;
    A_l[rr][kk] = load_in(A, (size_t)(r0 + rr) * lda + kk, f32);
  }
  const int c_l = t & 63, rg = t >> 6;
  for (int c0 = 0; c0 < C; c0 += 64) {
    __syncthreads();
    for (int idx = t; idx < 64 * 128; idx += 256) {
      int cc = idx >> 7, kk = idx & 127;
      W_l[cc][kk] = load_in(W, (size_t)w_off + (size_t)(c0 + cc) * ldw + kk, f32);
    }
    __syncthreads();
    float acc[4] = {0.f, 0.f, 0.f, 0.f};
    for (int k = 0; k < 128; k++) {
      float w = W_l[c_l][k];
#pragma unroll
      for (int x = 0; x < 4; x++) acc[x] = fmaf(A_l[rg * 4 + x][k], w, acc[x]);
    }
    float bv = load_in(bias, c0 + c_l, f32);
#pragma unroll
    for (int x = 0; x < 4; x++)
      out[(size_t)(r0 + rg * 4 + x) * C + c0 + c_l] = acc[x] + bv;
  }
}

// ---------------- actpack (R16 verbatim): TAp (tanh(whs) fp16, B-layout) +
// DWp (whs fp16, D-layout), both per-thread load-linear.
// 2*262144 u32 -> 2048 blocks x 256.
__global__ void actpack(const float* __restrict__ whs,
                        uint32_t* __restrict__ TAp, uint32_t* __restrict__ DWp) {
  int o = blockIdx.x * 256 + threadIdx.x;
  if (o < 262144) {
    int b = o >> 14, r = o & 16383;
    int c = r >> 2, w = r & 3;
    int i = c >> 10, t = c & 1023;
    int qB = t >> 2, hgB = t & 3;
    int h = hgB * 32 + i * 8 + w * 2;
    const float* base = whs + ((size_t)b * 256 + qB) * 128 + h;
    TAp[o] = f2h(tanhf(base[0]), tanhf(base[1]));
  } else {
    o -= 262144;
    int b = o >> 14, r2 = o & 16383;
    int i = r2 >> 12, r = r2 & 4095;
    int t = r >> 2, w = r & 3;
    int qgD = t & 7, hD = t >> 3;
    int q0 = qgD + 64 * i + 16 * w;
    const float* base = whs + (size_t)b * 32768;
    DWp[o] = f2h(base[(size_t)q0 * 128 + hD], base[(size_t)(q0 + 8) * 128 + hD]);
  }
}

// ---------------------------------------------------------- sequential kernel
#define TUIDX(j) ((((j) >> 5) * 36) + ((j) & 31))
#define SCIDX(q) ((((q) >> 5) * 36) + ((q) & 31))
#define AIDX(h)  ((((h) >> 5) * 36) + ((h) & 31))
#define HIDX(k)  ((((k) >> 4) * 20) + ((k) & 15))

__global__ __launch_bounds__(1024) void mlstm_seq16(
    const float* __restrict__ pf,      // [16][128][128]
    const float* __restrict__ wht_g,   // [16][128][128]
    const float* __restrict__ Gp_g,    // [16][128][256]
    const uint32_t* __restrict__ WrP,  // 8192 u32 load-linear
    const float* __restrict__ wrb,     // [128]
    const float* __restrict__ wew,     // [128]
    const float* __restrict__ web,     // [1]
    const uint32_t* __restrict__ WgP,  // 16384 u32 load-linear
    const uint32_t* __restrict__ WTP,  // 98304 u32 load-linear
    const uint32_t* __restrict__ TAp,  // [16] x 16384 u32
    const uint32_t* __restrict__ DWp,  // [16] x 16384 u32
    const float* __restrict__ bbv,     // [512]
    float* __restrict__ out) {         // [16][128][128]
  const int b = blockIdx.x, t = threadIdx.x;

  __shared__ __align__(16) uint4 tap_l[4096];     // 65536 B: tA fp16 (B)
  __shared__ __align__(16) uint4 dwp_l[4096];     // 65536 B: whs fp16 (D)
  __shared__ __align__(16) uint32_t xh_h2[192];   // [xh;h] as half2 pairs
  __shared__ __align__(16) float tu_s[144];
  __shared__ __align__(16) float wew_s[144];
  __shared__ __align__(16) float sc_s[288];
  __shared__ __align__(16) float e_s[256];
  __shared__ __align__(16) float alpha_s[144];
  __shared__ __align__(16) float h_s[160];
  __shared__ __align__(16) float gates_s[512];
  __shared__ float inv_s;

  const int jA = t >> 3, kgA = t & 7;   // A: 128 j x 8 kg (16 k)
  const int qB = t >> 2, hgB = t & 3;   // B: 256 q x 4 hg (32 h)
  const int hD = t >> 3, qgD = t & 7;   // D: 128 h x 8 qg (32 q interleaved)
  const int iE = t >> 2, kgE = t & 3;   // E: 256 i x 4 kg (32 k)
  const int iF = t >> 1, kgF = t & 1;   // F: 512 rows x 2 kg (192 k)

  const uint4* wrp4 = (const uint4*)WrP;                    // 2048 uint4
  const uint4* wgp4 = (const uint4*)WgP;                    // 4096 uint4
  const uint4* wtp4 = (const uint4*)WTP;                    // 24576 uint4
  const uint4* tap4 = (const uint4*)TAp + (size_t)b * 4096; // 4096 uint4
  const uint4* dwp4 = (const uint4*)DWp + (size_t)b * 4096; // 4096 uint4

  // ---- LDS init: tA + whs-fp16 (both per-batch constants) + small buffers
  for (int i = t; i < 4096; i += 1024) tap_l[i] = tap4[i];
  for (int i = t; i < 4096; i += 1024) dwp_l[i] = dwp4[i];
  if (t < 128) wew_s[TUIDX(t)] = wew[t];
  if (t < 160) h_s[t] = 0.f;
  if (t < 64) xh_h2[128 + t] = 0u;      // h half2 part, step 0

  const float wrb_r = wrb[jA];
  const float web_r = web[0];
  const float bbF_r = bbv[iF];
  float c_r = 0.f;                       // t<128 owners

  // per-step prefetch registers (rotate)
  float wht_c = (kgA == 0) ? wht_g[((size_t)b * 128 + 0) * 128 + jA] : 0.f;
  float gp_c  = (kgE == 0) ? Gp_g[((size_t)b * 128 + 0) * 256 + iE] : 0.f;
  float pf_c  = (kgE == 0 && iE >= 128) ? pf[((size_t)b * 128 + 0) * 128 + (iE - 128)] : 0.f;

  __syncthreads();

  for (int st = 0; st < 128; st++) {
    const int st1 = (st < 127) ? st + 1 : 127;
    float wht_n = (kgA == 0) ? wht_g[((size_t)b * 128 + st1) * 128 + jA] : 0.f;
    float gp_n  = (kgE == 0) ? Gp_g[((size_t)b * 128 + st1) * 256 + iE] : 0.f;
    float pf_n  = (kgE == 0 && iE >= 128) ? pf[((size_t)b * 128 + st1) * 128 + (iE - 128)] : 0.f;

    // ---- A: tu = tanh(h@Wr^T + wrb + wht)   [R15 verbatim]
    {
      float acc = 0.f;
#pragma unroll
      for (int i = 0; i < 2; i++) {
        uint4 wv = wrp4[i * 1024 + t];
        const float* hp = h_s + kgA * 20 + i * 8;
        float4 hA = *(const float4*)(hp);
        float4 hB = *(const float4*)(hp + 4);
        float2 w0 = h2f(wv.x), w1 = h2f(wv.y), w2 = h2f(wv.z), w3 = h2f(wv.w);
        acc = fmaf(hA.x, w0.x, acc); acc = fmaf(hA.y, w0.y, acc);
        acc = fmaf(hA.z, w1.x, acc); acc = fmaf(hA.w, w1.y, acc);
        acc = fmaf(hB.x, w2.x, acc); acc = fmaf(hB.y, w2.y, acc);
        acc = fmaf(hB.z, w3.x, acc); acc = fmaf(hB.w, w3.y, acc);
      }
      acc += __shfl_xor(acc, 1);
      acc += __shfl_xor(acc, 2);
      acc += __shfl_xor(acc, 4);
      if (kgA == 0) tu_s[TUIDX(jA)] = tanh_fast(acc + wrb_r + wht_c);
    }
    __syncthreads();

    // ---- B: sc[q] = sum_h we_h * (ta+tu)/(1+ta*tu)  [tA from LDS now]
    {
      float acc = 0.f;
#pragma unroll
      for (int i = 0; i < 4; i++) {
        uint4 av = tap_l[i * 1024 + t];
        const float* up = tu_s + hgB * 36 + i * 8;
        const float* wp = wew_s + hgB * 36 + i * 8;
        float4 uA = *(const float4*)(up);
        float4 uB = *(const float4*)(up + 4);
        float4 wA = *(const float4*)(wp);
        float4 wB = *(const float4*)(wp + 4);
        float2 a0 = h2f(av.x), a1 = h2f(av.y), a2 = h2f(av.z), a3 = h2f(av.w);
        acc = fmaf((a0.x + uA.x) * frcp(fmaxf(fmaf(a0.x, uA.x, 1.f), 1e-6f)), wA.x, acc);
        acc = fmaf((a0.y + uA.y) * frcp(fmaxf(fmaf(a0.y, uA.y, 1.f), 1e-6f)), wA.y, acc);
        acc = fmaf((a1.x + uA.z) * frcp(fmaxf(fmaf(a1.x, uA.z, 1.f), 1e-6f)), wA.z, acc);
        acc = fmaf((a1.y + uA.w) * frcp(fmaxf(fmaf(a1.y, uA.w, 1.f), 1e-6f)), wA.w, acc);
        acc = fmaf((a2.x + uB.x) * frcp(fmaxf(fmaf(a2.x, uB.x, 1.f), 1e-6f)), wB.x, acc);
        acc = fmaf((a2.y + uB.y) * frcp(fmaxf(fmaf(a2.y, uB.y, 1.f), 1e-6f)), wB.y, acc);
        acc = fmaf((a3.x + uB.z) * frcp(fmaxf(fmaf(a3.x, uB.z, 1.f), 1e-6f)), wB.z, acc);
        acc = fmaf((a3.y + uB.w) * frcp(fmaxf(fmaf(a3.y, uB.w, 1.f), 1e-6f)), wB.w, acc);
      }
      acc += __shfl_xor(acc, 1);
      acc += __shfl_xor(acc, 2);
      if (hgB == 0) sc_s[SCIDX(qB)] = acc + web_r;
    }
    __syncthreads();

    // ---- C: softmax stats + e_s (wave 0)   [R15 verbatim]
    if (t < 64) {
      float s0 = sc_s[SCIDX(t)],       s1 = sc_s[SCIDX(t + 64)];
      float s2 = sc_s[SCIDX(t + 128)], s3 = sc_s[SCIDX(t + 192)];
      float mx = fmaxf(fmaxf(s0, s1), fmaxf(s2, s3));
#pragma unroll
      for (int d = 1; d < 64; d <<= 1) mx = fmaxf(mx, __shfl_xor(mx, d));
      float e0 = __expf(s0 - mx), e1 = __expf(s1 - mx),
            e2 = __expf(s2 - mx), e3 = __expf(s3 - mx);
      float sum = e0 + e1 + e2 + e3;
#pragma unroll
      for (int d = 1; d < 64; d <<= 1) sum += __shfl_xor(sum, d);
      e_s[t] = e0; e_s[t + 64] = e1; e_s[t + 128] = e2; e_s[t + 192] = e3;
      if (t == 0) inv_s = frcp(sum);
    }
    __syncthreads();

    // ---- D: alpha = (sum_q e[q]*whs[q][h]) * inv   [R16's PASSED code,
    //      pointer swapped dwp4 -> dwp_l (LDS)]
    {
      float acc = 0.f;
#pragma unroll
      for (int i = 0; i < 4; i++) {
        uint4 v = dwp_l[i * 1024 + t];
        float2 s0 = h2f(v.x), s1 = h2f(v.y), s2 = h2f(v.z), s3 = h2f(v.w);
        const float* ep = e_s + qgD + 64 * i;
        acc = fmaf(ep[0],  s0.x, acc); acc = fmaf(ep[8],  s0.y, acc);
        acc = fmaf(ep[16], s1.x, acc); acc = fmaf(ep[24], s1.y, acc);
        acc = fmaf(ep[32], s2.x, acc); acc = fmaf(ep[40], s2.y, acc);
        acc = fmaf(ep[48], s3.x, acc); acc = fmaf(ep[56], s3.y, acc);
      }
      acc += __shfl_xor(acc, 1);
      acc += __shfl_xor(acc, 2);
      acc += __shfl_xor(acc, 4);
      if (qgD == 0) alpha_s[AIDX(hD)] = acc * inv_s;
    }
    __syncthreads();

    // ---- E: gate = sigmoid(Wg[:,:128]@alpha + Gp); xh_h2 pack  [R15 verbatim]
    {
      float acc = 0.f;
#pragma unroll
      for (int i = 0; i < 4; i++) {
        uint4 wv = wgp4[i * 1024 + t];
        const float* ap = alpha_s + kgE * 36 + i * 8;
        float4 aA = *(const float4*)(ap);
        float4 aB = *(const float4*)(ap + 4);
        float2 w0 = h2f(wv.x), w1 = h2f(wv.y), w2 = h2f(wv.z), w3 = h2f(wv.w);
        acc = fmaf(aA.x, w0.x, acc); acc = fmaf(aA.y, w0.y, acc);
        acc = fmaf(aA.z, w1.x, acc); acc = fmaf(aA.w, w1.y, acc);
        acc = fmaf(aB.x, w2.x, acc); acc = fmaf(aB.y, w2.y, acc);
        acc = fmaf(aB.z, w3.x, acc); acc = fmaf(aB.w, w3.y, acc);
      }
      acc += __shfl_xor(acc, 1);
      acc += __shfl_xor(acc, 2);
      float v = 0.f;
      if (kgE == 0) {
        float sg = sigm(gp_c + acc);
        float xv = (iE < 128) ? alpha_s[AIDX(iE)] : pf_c;
        v = sg * xv;
      }
      float vp = __shfl_xor(v, 4);              // partner iE^1 (kgE==0 lanes)
      if (kgE == 0 && (iE & 1) == 0) xh_h2[iE >> 1] = f2h(v, vp);
    }
    __syncthreads();

    // ---- F: gates = WT@[xh;h] via dot2, compiler-scheduled direct loads
    //      [R15 verbatim]
    {
      const uint4* xv4 = (const uint4*)xh_h2;   // 48 uint4 (broadcast reads)
      float acc = 0.f;
#pragma unroll 8
      for (int i = 0; i < 24; i++) {
        uint4 wv = wtp4[i * 1024 + t];
        uint4 xv = xv4[kgF * 24 + i];
        acc = dot2(wv.x, xv.x, acc); acc = dot2(wv.y, xv.y, acc);
        acc = dot2(wv.z, xv.z, acc); acc = dot2(wv.w, xv.w, acc);
      }
      acc += __shfl_xor(acc, 1);
      if (kgF == 0) gates_s[iF] = acc + bbF_r;
    }
    __syncthreads();

    // ---- cell: c in regs; h -> h_s fp32 + xh_h2 fp16 pairs; out [R15 verbatim]
    if (t < 128) {
      float iv = sigm(gates_s[t]);
      float fv = sigm(gates_s[128 + t]);
      float gv = tanh_fast(gates_s[256 + t]);
      float ov = sigm(gates_s[384 + t]);
      float cn = fmaf(fv, c_r, iv * gv);
      float hn = ov * tanh_fast(cn);
      c_r = cn;
      h_s[HIDX(t)] = hn;
      float hp = __shfl_xor(hn, 1);
      if ((t & 1) == 0) xh_h2[128 + (t >> 1)] = f2h(hn, hp);
      out[((size_t)b * 128 + st) * 128 + t] = hn;
    }
    __syncthreads();

    wht_c = wht_n; gp_c = gp_n; pf_c = pf_n;
  }
}

// ----------------------------------------------------------------- launcher
extern "C" void kernel_launch(void* const* d_in, const int* in_sizes, int n_in,
                              void* d_out, int out_size, void* d_ws, size_t ws_size,
                              hipStream_t stream) {
  static const int SZ_DICT[18] = {262144, 524288, 16384, 128, 16384, 128,
                                  16384, 128, 128, 1, 65536, 256,
                                  131072, 65536, 512, 512, 2048, 4096};
  static const int ALPHA2DICT[18] = {9, 8, 11, 10, 13, 12, 7, 6, 3, 2, 5, 4,
                                     15, 14, 0, 16, 1, 17};
  const void* in[18];
  for (int i = 0; i < 18; i++) in[i] = (i < n_in) ? d_in[i] : nullptr;

  bool dict_ok = true;
  int lim = (n_in < 16) ? n_in : 16;
  for (int i = 0; i < lim; i++) if (in_sizes[i] != SZ_DICT[i]) dict_ok = false;
  if (!dict_ok) {
    bool alpha_ok = true;
    for (int s = 0; s < n_in && s < 18; s++)
      if (in_sizes[s] != SZ_DICT[ALPHA2DICT[s]]) alpha_ok = false;
    if (alpha_ok)
      for (int s = 0; s < n_in && s < 18; s++) in[ALPHA2DICT[s]] = d_in[s];
  }

  const void* p   = in[0];  const void* q   = in[1];
  const void* Wsw = in[2];  const void* Wsb = in[3];
  const void* Wtw = in[4];  const void* Wtb = in[5];
  const void* Wrw = in[6];  const void* Wrb = in[7];
  const void* Wew = in[8];  const void* Web = in[9];
  const void* Wgw = in[10]; const void* Wgb = in[11];
  const void* Wih = in[12]; const void* Whh = in[13];
  const void* bih = in[14]; const void* bhh = in[15];

  float* ws = (float*)d_ws;
  float* whs  = ws;                          // 524288
  float* pff  = whs + 524288;                // 262144
  float* wht  = pff + 262144;                // 262144
  float* Gp   = wht + 262144;                // 524288
  uint32_t* WrP = (uint32_t*)(Gp + 524288);  // 8192
  uint32_t* WgP = WrP + 8192;                // 16384
  uint32_t* WTP = WgP + 16384;               // 98304
  uint32_t* TAp = WTP + 98304;               // 262144
  uint32_t* DWp = TAp + 262144;              // 262144
  float* bbv  = (float*)(DWp + 262144);      // 512
  float* wrb  = bbv + 512;                   // 128
  float* wew  = wrb + 128;                   // 128
  float* web  = wew + 128;                   // 4 (1 used)
  uint32_t* flag = (uint32_t*)(web + 4);     // 4     (~8.8 MB total)

  hipLaunchKernelGGL(detect_kernel, dim3(1), dim3(256), 0, stream,
                     (const uint16_t*)q, flag);
  // 385793 init elements -> 1508 blocks x 256
  hipLaunchKernelGGL(pack2, dim3(1508), dim3(256), 0, stream,
                     p, Wrw, Wrb, Wew, Web, Wgw, Wih, Whh, bih, bhh,
                     pff, WrP, wrb, wew, web, WgP, WTP, bbv, flag);
  hipLaunchKernelGGL(gemm3, dim3(512), dim3(256), 0, stream,
                     q, p, Wsw, Wsb, Wtw, Wtb, Wgw, Wgb, whs, wht, Gp, flag);
  // 524288 outputs -> 2048 blocks x 256
  hipLaunchKernelGGL(actpack, dim3(2048), dim3(256), 0, stream, whs, TAp, DWp);
  hipLaunchKernelGGL(mlstm_seq16, dim3(16), dim3(1024), 0, stream,
                     pff, wht, Gp, WrP, wrb, wew, web, WgP, WTP, TAp, DWp, bbv,
                     (float*)d_out);
}